// Round 4
// baseline (649.009 us; speedup 1.0000x reference)
//
#include <hip/hip_runtime.h>

#define SEQ  720
#define PRED 720
#define RANK 16
#define CTXD 128
#define HID  64
#define BATCH 256
#define ODIM  (RANK * (SEQ + PRED))   // 23040
#define ASIZE (RANK * PRED)           // 11520

#define ST 256                 // s-cols per k_weff block (3 tiles, last masked)
#define RPWAVE (PRED / 4)      // p-rows per wave = 180

typedef float v4f __attribute__((ext_vector_type(4)));

#define FMA4(ci, av, bv)                 \
    ci.x = fmaf(av, bv.x, ci.x);         \
    ci.y = fmaf(av, bv.y, ci.y);         \
    ci.z = fmaf(av, bv.z, ci.z);         \
    ci.w = fmaf(av, bv.w, ci.w);

// ---------------------------------------------------------------------------
// K1: hidden[b,k] = relu(ctx[b,:] @ W1[k,:] + b1[k]);  (256, 64)
// ---------------------------------------------------------------------------
__global__ __launch_bounds__(64) void k_hidden(const float* __restrict__ ctx,
                                               const float* __restrict__ W1,
                                               const float* __restrict__ b1,
                                               float* __restrict__ hid)
{
    __shared__ alignas(16) float cl[CTXD];
    int b = blockIdx.x, k = threadIdx.x;
    cl[k]      = ctx[b * CTXD + k];
    cl[k + 64] = ctx[b * CTXD + k + 64];
    __syncthreads();
    float acc = b1[k];
    const float* wr = W1 + k * CTXD;
#pragma unroll
    for (int c = 0; c < CTXD; c += 4) {
        float4 w  = *(const float4*)(wr + c);
        float4 xv = *(const float4*)(cl + c);
        acc = fmaf(w.x, xv.x, acc);
        acc = fmaf(w.y, xv.y, acc);
        acc = fmaf(w.z, xv.z, acc);
        acc = fmaf(w.w, xv.w, acc);
    }
    hid[b * HID + k] = fmaxf(acc, 0.0f);
}

// ---------------------------------------------------------------------------
// K2: h[b,o] = hidden[b,:] @ W2[o,:] + b2[o];  (256, 23040)
// grid (ODIM/64, BATCH/64), 256 threads, 64x64 tile, 4x4 per thread.
// ---------------------------------------------------------------------------
__global__ __launch_bounds__(256) void k_hyper(const float* __restrict__ hid,
                                               const float* __restrict__ W2,
                                               const float* __restrict__ b2,
                                               float* __restrict__ h)
{
    int ot = blockIdx.x, bt = blockIdx.y;
    __shared__ alignas(16) float Hl[64 * 68];   // [b_local][k], pad 68 -> 2-way (free)
    __shared__ alignas(16) float Wl[64 * 68];   // [o_local][k]
    int tid = threadIdx.x;

    const float* hg = hid + (size_t)bt * 64 * HID;   // contiguous 4096 floats
    const float* wg = W2  + (size_t)ot * 64 * HID;   // contiguous 4096 floats
#pragma unroll
    for (int n = 0; n < 4; n++) {
        int g = tid * 4 + n * 1024;
        float4 hv = *(const float4*)(hg + g);
        float4 wv = *(const float4*)(wg + g);
        int row = g >> 6, colk = g & 63;
        *(float4*)&Hl[row * 68 + colk] = hv;
        *(float4*)&Wl[row * 68 + colk] = wv;
    }
    __syncthreads();

    int tx = tid & 15, ty = tid >> 4;
    float c[4][4];
#pragma unroll
    for (int j = 0; j < 4; j++) {
        float bv = b2[ot * 64 + j * 16 + tx];
        c[0][j] = bv; c[1][j] = bv; c[2][j] = bv; c[3][j] = bv;
    }
#pragma unroll
    for (int kc = 0; kc < HID; kc += 4) {
        float4 hv[4], wv[4];
#pragma unroll
        for (int i = 0; i < 4; i++) hv[i] = *(const float4*)&Hl[(ty * 4 + i) * 68 + kc];
#pragma unroll
        for (int j = 0; j < 4; j++) wv[j] = *(const float4*)&Wl[(j * 16 + tx) * 68 + kc];
#pragma unroll
        for (int i = 0; i < 4; i++)
#pragma unroll
            for (int j = 0; j < 4; j++) {
                c[i][j] = fmaf(hv[i].x, wv[j].x, c[i][j]);
                c[i][j] = fmaf(hv[i].y, wv[j].y, c[i][j]);
                c[i][j] = fmaf(hv[i].z, wv[j].z, c[i][j]);
                c[i][j] = fmaf(hv[i].w, wv[j].w, c[i][j]);
            }
    }
#pragma unroll
    for (int i = 0; i < 4; i++) {
        int b = bt * 64 + ty * 4 + i;
        float* hb = h + (size_t)b * ODIM + ot * 64;
#pragma unroll
        for (int j = 0; j < 4; j++)
            hb[j * 16 + tx] = c[i][j];
    }
}

// ---------------------------------------------------------------------------
// K_Y: y[b,p] = dot(W[p,:], x[b,:]) + dot(A[b,p,:], Bx[b,:])
//      where Bx[b,r] = dot(B[b,r,:], x[b,:])
// Algebraically identical to einsum(W_eff, x); avoids touching W_eff.
// One block per batch. W is 2 MB -> L2-resident broadcast read.
// ---------------------------------------------------------------------------
__global__ __launch_bounds__(256) void k_y(const float* __restrict__ h,
                                           const float* __restrict__ W,
                                           const float* __restrict__ x,
                                           float* __restrict__ y)
{
    const int b = blockIdx.x, tid = threadIdx.x;
    __shared__ alignas(16) float xs[SEQ];     // 720
    __shared__ float red[256];
    __shared__ float bxs[RANK];
    const float* hb = h + (size_t)b * ODIM;

    if (tid < SEQ / 4)
        *(float4*)&xs[tid * 4] = *(const float4*)(x + (size_t)b * SEQ + tid * 4);
    __syncthreads();

    // Bx[r] = sum_s B[b,r,s]*x[b,s]; 16 r-rows x 16 col-chunks of 45
    {
        const int r = tid >> 4, c = tid & 15;
        const float* brow = hb + ASIZE + r * SEQ + c * 45;
        float part = 0.0f;
#pragma unroll
        for (int i = 0; i < 45; i++) part = fmaf(brow[i], xs[c * 45 + i], part);
        red[tid] = part;
    }
    __syncthreads();
    if (tid < RANK) {
        float s = 0.0f;
#pragma unroll
        for (int j = 0; j < 16; j++) s += red[tid * 16 + j];
        bxs[tid] = s;
    }
    __syncthreads();

    for (int p = tid; p < PRED; p += 256) {
        const float* wr = W + (size_t)p * SEQ;
        float acc = 0.0f;
#pragma unroll 4
        for (int c4 = 0; c4 < SEQ; c4 += 4) {
            float4 wv = *(const float4*)(wr + c4);
            acc = fmaf(wv.x, xs[c4],     acc);
            acc = fmaf(wv.y, xs[c4 + 1], acc);
            acc = fmaf(wv.z, xs[c4 + 2], acc);
            acc = fmaf(wv.w, xs[c4 + 3], acc);
        }
        const float* ar = hb + p * RANK;
#pragma unroll
        for (int r = 0; r < RANK; r++) acc = fmaf(ar[r], bxs[r], acc);
        y[(size_t)b * PRED + p] = acc;
    }
}

// ---------------------------------------------------------------------------
// K3: W_eff[b,p,s] = W[p,s] + sum_r A[b,p,r]*B[b,r,s]  — long-lived stream.
// grid (3 s-tiles x 256 batches) = 768 blocks = 3 blocks/CU.
// Key: the B-slice depends only on (b, s-range) -> each lane keeps its
// B column slice B[0..15][s..s+3] in 64 VGPRs, loaded ONCE. The A-panel
// (720x16 = 46 KB) is staged to LDS once. Then the block streams all 720
// p-rows: 4 LDS broadcasts + 1 L2-hit W load + 64 FMA + one contiguous
// 1 KB wave nontemporal store per row. Store duty cycle is near-continuous
// (vs 34560 short blocks each paying a staging latency chain for 16 KB).
// A[b,p,r] = h[b, p*16+r];  B[b,r,s] = h[b, 11520 + r*720 + s]
// ---------------------------------------------------------------------------
__global__ __launch_bounds__(256, 3) void k_weff(const float* __restrict__ h,
                                                 const float* __restrict__ W,
                                                 float* __restrict__ weff)
{
    const int st = blockIdx.x, b = blockIdx.y;
    const int s0 = st * ST;
    __shared__ alignas(16) float Al[PRED * RANK];   // 46080 B
    const int tid = threadIdx.x;
    const float* hb = h + (size_t)b * ODIM;

    // stage the whole A panel for this batch: 11520 contiguous floats
    for (int i = tid; i < ASIZE / 4; i += 256)
        *(float4*)&Al[i * 4] = *(const float4*)(hb + i * 4);

    const int wave = tid >> 6, lane = tid & 63;
    const int s = s0 + lane * 4;
    const bool sv = (s < SEQ);
    const int sc = sv ? s : (SEQ - 4);      // clamped addr for W loads

    // B column slice in registers (zero past SEQ; load predicated to stay
    // inside this batch's h slice)
    float4 Bv[RANK];
#pragma unroll
    for (int r = 0; r < RANK; r++) {
        float4 v = make_float4(0.f, 0.f, 0.f, 0.f);
        if (sv) v = *(const float4*)(hb + ASIZE + r * SEQ + s);
        Bv[r] = v;
    }
    __syncthreads();

    const int p0 = wave * RPWAVE;           // this wave's 180 contiguous rows
    const float* wrow = W + (size_t)p0 * SEQ + sc;
    const float* arow = Al + p0 * RANK;
    float* orow = weff + (size_t)b * ((size_t)PRED * SEQ) + (size_t)p0 * SEQ + s;

#pragma unroll 2
    for (int i = 0; i < RPWAVE; ++i) {
        float4 wv = *(const float4*)wrow;   // L2-resident (W = 2 MB)
        v4f e;
        e.x = wv.x; e.y = wv.y; e.z = wv.z; e.w = wv.w;
#pragma unroll
        for (int rc = 0; rc < RANK; rc += 4) {
            // uniform address across the wave -> LDS broadcast, conflict-free
            float4 a = *(const float4*)(arow + rc);
            FMA4(e, a.x, Bv[rc]);
            FMA4(e, a.y, Bv[rc + 1]);
            FMA4(e, a.z, Bv[rc + 2]);
            FMA4(e, a.w, Bv[rc + 3]);
        }
        if (sv) __builtin_nontemporal_store(e, (v4f*)orow);
        wrow += SEQ;
        arow += RANK;
        orow += SEQ;
    }
}

// ---------------------------------------------------------------------------
extern "C" void kernel_launch(void* const* d_in, const int* in_sizes, int n_in,
                              void* d_out, int out_size, void* d_ws, size_t ws_size,
                              hipStream_t stream)
{
    const float* x   = (const float*)d_in[0];
    const float* ctx = (const float*)d_in[1];
    const float* W   = (const float*)d_in[2];
    const float* W1  = (const float*)d_in[3];
    const float* b1  = (const float*)d_in[4];
    const float* W2  = (const float*)d_in[5];
    const float* b2  = (const float*)d_in[6];

    float* out  = (float*)d_out;
    float* yout = out;                                  // (256, 720, 1)
    float* weff = out + (size_t)BATCH * PRED;           // (256, 720, 720)

    float* hid = (float*)d_ws;                          // 256*64 floats
    float* h   = hid + (size_t)BATCH * HID;             // 256*23040 floats

    k_hidden<<<dim3(BATCH), dim3(64), 0, stream>>>(ctx, W1, b1, hid);
    k_hyper<<<dim3(ODIM / 64, BATCH / 64), dim3(256), 0, stream>>>(hid, W2, b2, h);
    k_y<<<dim3(BATCH), dim3(256), 0, stream>>>(h, W, x, yout);
    k_weff<<<dim3(3, BATCH), dim3(256), 0, stream>>>(h, W, weff);
}